// Round 1
// baseline (4240.430 us; speedup 1.0000x reference)
//
#include <hip/hip_runtime.h>
#include <cmath>

// Scattering transform, two orders. B=32, C=3, P=8, 512x512 in, 7x7 filters, pad 3.
// Both stages are the same fused op: per input channel gq (filter bank index gq%3):
//   - phi conv stride 2            -> out channel gq
//   - 8x (psi_r,psi_i) conv stride 2, modulus, phi-smooth stride 1
//                                  -> out channels Cin + gq*8 + j
// Stage 1: in = x        [32][ 3][512][512] -> s1  [32][ 27][256][256] (workspace)
// Stage 2: in = s1       [32][27][256][256] -> out [32][243][128][128]

#define TILE 32
#define UH   38   // TILE + 6 (3-px halo each side for the smoothing conv)
#define US   39   // padded LDS row stride for u tiles
#define XT   81   // 2*TILE + 17 input rows/cols needed per tile

__global__ void pack_weights_kernel(const float* __restrict__ psi_r,
                                    const float* __restrict__ psi_i,
                                    float* __restrict__ wpack) {
  // wpack layout: [g=3][tap=49][j=8][{r,i}=2]  (16 consecutive floats per tap)
  int idx = blockIdx.x * 256 + threadIdx.x;
  if (idx >= 3 * 49 * 8) return;
  int j   = idx % 8;
  int tap = (idx / 8) % 49;
  int g   = idx / (8 * 49);
  int src = (g * 8 + j) * 49 + tap;
  wpack[idx * 2 + 0] = psi_r[src];
  wpack[idx * 2 + 1] = psi_i[src];
}

__global__ __launch_bounds__(256) void scatter_stage_kernel(
    const float* __restrict__ in,     // [B][Cin][Hin][Win]
    const float* __restrict__ phi,    // [3][49]
    const float* __restrict__ wpack,  // [3][49][8][2]
    float* __restrict__ out,          // [B][Cin*9][Hin/2][Win/2]
    int Cin, int Hin, int Win, int tilesX)
{
  const int Hout = Hin >> 1, Wout = Win >> 1;
  const int gq  = blockIdx.y;
  const int b   = blockIdx.z;
  const int ty0 = (blockIdx.x / tilesX) * TILE;
  const int tx0 = (blockIdx.x % tilesX) * TILE;
  const int g3  = gq % 3;
  const int tid = threadIdx.x;

  __shared__ float xs[XT][XT];      // 26244 B
  __shared__ float us[4][UH][US];   // 23712 B  (total ~50 KB -> 3 blocks/CU)

  const float* __restrict__ inp =
      in + ((size_t)b * Cin + gq) * ((size_t)Hin * Win);
  float* __restrict__ outp =
      out + (size_t)b * (size_t)(Cin * 9) * (size_t)(Hout * Wout);

  // ---- load input tile (zero-padded) ----
  const int iy0 = 2 * ty0 - 9;   // = 2*(ty0-3) - 3
  const int ix0 = 2 * tx0 - 9;
  for (int i = tid; i < XT * XT; i += 256) {
    int r = i / XT, c = i - r * XT;
    int gy = iy0 + r, gx = ix0 + c;
    float v = 0.0f;
    if ((unsigned)gy < (unsigned)Hin && (unsigned)gx < (unsigned)Win)
      v = inp[(size_t)gy * Win + gx];
    xs[r][c] = v;
  }
  __syncthreads();

  // ---- phi low-pass, stride 2 -> out channel gq ----
  {
    const float* __restrict__ wph = phi + g3 * 49;
    for (int i = tid; i < TILE * TILE; i += 256) {
      int oy = i >> 5, ox = i & 31;
      float acc = 0.0f;
      #pragma unroll
      for (int ky = 0; ky < 7; ky++)
        #pragma unroll
        for (int kx = 0; kx < 7; kx++)
          acc = fmaf(xs[2 * oy + 6 + ky][2 * ox + 6 + kx], wph[ky * 7 + kx], acc);
      outp[((size_t)gq * Hout + (ty0 + oy)) * Wout + (tx0 + ox)] = acc;
    }
  }

  // ---- band-pass modulus + smoothing, 4 psi filters per half ----
  for (int half = 0; half < 2; half++) {
    __syncthreads();
    const float* __restrict__ wp = wpack + g3 * 49 * 16 + half * 8;
    for (int i = tid; i < UH * UH; i += 256) {
      int uy = i / UH, ux = i - uy * UH;
      int uyg = ty0 - 3 + uy, uxg = tx0 - 3 + ux;
      float ar0 = 0, ai0 = 0, ar1 = 0, ai1 = 0;
      float ar2 = 0, ai2 = 0, ar3 = 0, ai3 = 0;
      #pragma unroll
      for (int ky = 0; ky < 7; ky++) {
        #pragma unroll
        for (int kx = 0; kx < 7; kx++) {
          float xv = xs[2 * uy + ky][2 * ux + kx];
          const float* __restrict__ w = wp + (ky * 7 + kx) * 16; // wave-uniform -> s_load
          ar0 = fmaf(xv, w[0], ar0); ai0 = fmaf(xv, w[1], ai0);
          ar1 = fmaf(xv, w[2], ar1); ai1 = fmaf(xv, w[3], ai1);
          ar2 = fmaf(xv, w[4], ar2); ai2 = fmaf(xv, w[5], ai2);
          ar3 = fmaf(xv, w[6], ar3); ai3 = fmaf(xv, w[7], ai3);
        }
      }
      // positions outside the valid stride-2 grid contribute zero (conv padding)
      bool valid = ((unsigned)uyg < (unsigned)Hout) & ((unsigned)uxg < (unsigned)Wout);
      us[0][uy][ux] = valid ? sqrtf(ar0 * ar0 + ai0 * ai0) : 0.0f;
      us[1][uy][ux] = valid ? sqrtf(ar1 * ar1 + ai1 * ai1) : 0.0f;
      us[2][uy][ux] = valid ? sqrtf(ar2 * ar2 + ai2 * ai2) : 0.0f;
      us[3][uy][ux] = valid ? sqrtf(ar3 * ar3 + ai3 * ai3) : 0.0f;
    }
    __syncthreads();

    for (int j4 = 0; j4 < 4; j4++) {
      const int j  = half * 4 + j4;
      const int pf = (gq * 8 + j) % 3;     // tiled-phi filter index
      const float* __restrict__ wsm = phi + pf * 49;
      const int ch = Cin + gq * 8 + j;
      for (int i = tid; i < TILE * TILE; i += 256) {
        int oy = i >> 5, ox = i & 31;
        float acc = 0.0f;
        #pragma unroll
        for (int ky = 0; ky < 7; ky++)
          #pragma unroll
          for (int kx = 0; kx < 7; kx++)
            acc = fmaf(us[j4][oy + ky][ox + kx], wsm[ky * 7 + kx], acc);
        outp[((size_t)ch * Hout + (ty0 + oy)) * Wout + (tx0 + ox)] = acc;
      }
    }
  }
}

extern "C" void kernel_launch(void* const* d_in, const int* in_sizes, int n_in,
                              void* d_out, int out_size, void* d_ws, size_t ws_size,
                              hipStream_t stream) {
  const float* x     = (const float*)d_in[0];  // [32][3][512][512]
  const float* phi   = (const float*)d_in[1];  // [3][1][7][7]
  const float* psi_r = (const float*)d_in[2];  // [24][1][7][7]
  const float* psi_i = (const float*)d_in[3];  // [24][1][7][7]
  float* out = (float*)d_out;                  // [32][243][128][128]

  float* s1    = (float*)d_ws;                           // [32][27][256][256] = 226.5 MB
  float* wpack = s1 + (size_t)32 * 27 * 256 * 256;       // 2352 floats

  pack_weights_kernel<<<dim3(5), 256, 0, stream>>>(psi_r, psi_i, wpack);

  // Stage 1: x -> s1   (Cin=3, 512x512 -> 256x256; 8x8 tiles)
  scatter_stage_kernel<<<dim3(64, 3, 32), 256, 0, stream>>>(
      x, phi, wpack, s1, 3, 512, 512, 8);

  // Stage 2: s1 -> out (Cin=27, 256x256 -> 128x128; 4x4 tiles)
  scatter_stage_kernel<<<dim3(16, 27, 32), 256, 0, stream>>>(
      s1, phi, wpack, out, 27, 256, 256, 4);
}